// Round 5
// baseline (22.106 us; speedup 1.0000x reference)
//
#include <hip/hip_runtime.h>

// BiorUpSampling: 2x zero-interleaved upsample + separable symmetric 9-tap
// filter, SAME zero padding. Polyphase, register-streaming 5-row ring.
// RP=4 -> 2048 blocks -> 8 blocks/CU -> 32 waves/CU (max occupancy) to
// maximize outstanding memory ops; __launch_bounds__(256,8) pins VGPR<=64.

constexpr int H = 512, W = 512;
constexpr int RP = 4;   // input rows advanced per block -> 8 output rows

typedef float f32x4 __attribute__((ext_vector_type(4)));

__global__ __launch_bounds__(256, 8)
void bior_up_kernel(const float* __restrict__ in, float* __restrict__ out) {
  constexpr float E0 =  0.03782845550699535f;
  constexpr float E1 = -0.1106244044184226f;
  constexpr float E2 =  0.8526986790094022f;
  constexpr float E3 = -0.1106244044184226f;
  constexpr float E4 =  0.03782845550699535f;
  constexpr float O0 = -0.02384946501937986f;
  constexpr float O1 =  0.3774028556126536f;
  constexpr float O2 =  0.3774028556126537f;
  constexpr float O3 = -0.02384946501937986f;

  const int tid = threadIdx.x;
  const int r0  = blockIdx.x * RP;
  const int b   = blockIdx.y;
  const float* inb  = in  + (size_t)b * H * W;
  float*       outb = out + (size_t)b * (2 * H) * (2 * W);

  const int c = 2 * tid;              // this thread's input cols: c, c+1
  const bool lv = (c >= 2);
  const bool rv = (c <= W - 4);

  // Ring of horizontally-filtered rows.
  // A=he(c)->out 2c, B=ho(c)->2c+1, C=he(c+1)->2c+2, D=ho(c+1)->2c+3
  float A[5], B[5], C[5], D[5];

#define HROW(GR, AI, BI, CI, DI)                                              \
  {                                                                           \
    const int _gr = (GR);                                                     \
    const bool rowv = ((unsigned)_gr < (unsigned)H);                          \
    const float* rowp = inb + (size_t)_gr * W;                                \
    const float2 z = make_float2(0.0f, 0.0f);                                 \
    const float2 Lq = (rowv && lv) ? *reinterpret_cast<const float2*>(rowp + c - 2) : z; \
    const float2 Mq =  rowv        ? *reinterpret_cast<const float2*>(rowp + c)     : z; \
    const float2 Rq = (rowv && rv) ? *reinterpret_cast<const float2*>(rowp + c + 2) : z; \
    const float v0 = Lq.x, v1 = Lq.y, v2 = Mq.x, v3 = Mq.y, v4 = Rq.x, v5 = Rq.y; \
    AI = v0*E0 + v1*E1 + v2*E2 + v3*E3 + v4*E4;                               \
    BI = v1*O0 + v2*O1 + v3*O2 + v4*O3;                                       \
    CI = v1*E0 + v2*E1 + v3*E2 + v4*E3 + v5*E4;                               \
    DI = v2*O0 + v3*O1 + v4*O2 + v5*O3;                                       \
  }

  // Prologue: rows r0-2 .. r0+1 into slots 0..3.
  HROW(r0 - 2, A[0], B[0], C[0], D[0]);
  HROW(r0 - 1, A[1], B[1], C[1], D[1]);
  HROW(r0    , A[2], B[2], C[2], D[2]);
  HROW(r0 + 1, A[3], B[3], C[3], D[3]);

#pragma unroll
  for (int p = 0; p < RP; ++p) {
    HROW(r0 + 2 + p, A[4], B[4], C[4], D[4]);

    f32x4 ev, od;
    ev.x = A[0]*E0 + A[1]*E1 + A[2]*E2 + A[3]*E3 + A[4]*E4;
    ev.y = B[0]*E0 + B[1]*E1 + B[2]*E2 + B[3]*E3 + B[4]*E4;
    ev.z = C[0]*E0 + C[1]*E1 + C[2]*E2 + C[3]*E3 + C[4]*E4;
    ev.w = D[0]*E0 + D[1]*E1 + D[2]*E2 + D[3]*E3 + D[4]*E4;
    od.x = A[1]*O0 + A[2]*O1 + A[3]*O2 + A[4]*O3;
    od.y = B[1]*O0 + B[2]*O1 + B[3]*O2 + B[4]*O3;
    od.z = C[1]*O0 + C[2]*O1 + C[3]*O2 + C[4]*O3;
    od.w = D[1]*O0 + D[2]*O1 + D[3]*O2 + D[4]*O3;

    const int row_e = 2 * (r0 + p);
    f32x4* pe = reinterpret_cast<f32x4*>(&outb[(size_t)row_e       * (2 * W) + 4 * tid]);
    f32x4* po = reinterpret_cast<f32x4*>(&outb[(size_t)(row_e + 1) * (2 * W) + 4 * tid]);
    __builtin_nontemporal_store(ev, pe);   // write-once output: keep L2 for input
    __builtin_nontemporal_store(od, po);

#pragma unroll
    for (int k = 0; k < 4; ++k) {
      A[k] = A[k + 1]; B[k] = B[k + 1]; C[k] = C[k + 1]; D[k] = D[k + 1];
    }
  }
#undef HROW
}

extern "C" void kernel_launch(void* const* d_in, const int* in_sizes, int n_in,
                              void* d_out, int out_size, void* d_ws, size_t ws_size,
                              hipStream_t stream) {
  const float* in = (const float*)d_in[0];
  float* out = (float*)d_out;
  const int batch = in_sizes[0] / (H * W);
  dim3 grid(H / RP, batch);   // 128 x 16 = 2048 blocks -> 8 blocks/CU
  bior_up_kernel<<<grid, 256, 0, stream>>>(in, out);
}

// Round 6
// 19.118 us; speedup vs baseline: 1.1563x; 1.1563x over previous
//
#include <hip/hip_runtime.h>

// BiorUpSampling: 2x zero-interleaved upsample + separable symmetric 9-tap
// filter, SAME zero padding. Polyphase, register-streaming 5-row ring with a
// 1-deep explicit load pipeline: row p+1's loads are issued before row p's
// compute+store, so vmcnt waits land a full iteration after issue.
// NT stores keep the write-once 64MB output from thrashing L2.

constexpr int H = 512, W = 512;
constexpr int RP = 8;   // input rows advanced per block -> 16 output rows

typedef float f32x4 __attribute__((ext_vector_type(4)));

__global__ __launch_bounds__(256)
void bior_up_kernel(const float* __restrict__ in, float* __restrict__ out) {
  constexpr float E0 =  0.03782845550699535f;
  constexpr float E1 = -0.1106244044184226f;
  constexpr float E2 =  0.8526986790094022f;
  constexpr float E3 = -0.1106244044184226f;
  constexpr float E4 =  0.03782845550699535f;
  constexpr float O0 = -0.02384946501937986f;
  constexpr float O1 =  0.3774028556126536f;
  constexpr float O2 =  0.3774028556126537f;
  constexpr float O3 = -0.02384946501937986f;

  const int tid = threadIdx.x;
  const int r0  = blockIdx.x * RP;
  const int b   = blockIdx.y;
  const float* inb  = in  + (size_t)b * H * W;
  float*       outb = out + (size_t)b * (2 * H) * (2 * W);

  const int c = 2 * tid;              // this thread's input cols: c, c+1
  const bool lv = (c >= 2);
  const bool rv = (c <= W - 4);

  auto loadrow = [&](int gr, float2& L, float2& M, float2& R) {
    const bool rowv = ((unsigned)gr < (unsigned)H);
    const float* rowp = inb + (size_t)gr * W;
    const float2 z = make_float2(0.0f, 0.0f);
    L = (rowv && lv) ? *reinterpret_cast<const float2*>(rowp + c - 2) : z;
    M =  rowv        ? *reinterpret_cast<const float2*>(rowp + c)     : z;
    R = (rowv && rv) ? *reinterpret_cast<const float2*>(rowp + c + 2) : z;
  };
  auto hfilt = [&](float2 L, float2 M, float2 R,
                   float& a, float& bb, float& cc, float& dd) {
    const float v0 = L.x, v1 = L.y, v2 = M.x, v3 = M.y, v4 = R.x, v5 = R.y;
    a  = v0*E0 + v1*E1 + v2*E2 + v3*E3 + v4*E4;   // he(c)   -> out col 2c
    bb = v1*O0 + v2*O1 + v3*O2 + v4*O3;           // ho(c)   -> out col 2c+1
    cc = v1*E0 + v2*E1 + v3*E2 + v4*E3 + v5*E4;   // he(c+1) -> out col 2c+2
    dd = v2*O0 + v3*O1 + v4*O2 + v5*O3;           // ho(c+1) -> out col 2c+3
  };

  // Ring of horizontally-filtered rows; slot k holds row (center-2+k).
  float A[5], B[5], C[5], D[5];

  // Prologue: issue all 4 halo/lead row loads back-to-back, then compute.
  float2 La, Ma, Ra, Lb, Mb, Rb, Lc, Mc, Rc, Ld, Md, Rd;
  loadrow(r0 - 2, La, Ma, Ra);
  loadrow(r0 - 1, Lb, Mb, Rb);
  loadrow(r0    , Lc, Mc, Rc);
  loadrow(r0 + 1, Ld, Md, Rd);
  hfilt(La, Ma, Ra, A[0], B[0], C[0], D[0]);
  hfilt(Lb, Mb, Rb, A[1], B[1], C[1], D[1]);
  hfilt(Lc, Mc, Rc, A[2], B[2], C[2], D[2]);
  hfilt(Ld, Md, Rd, A[3], B[3], C[3], D[3]);

  // Pipeline register set: loads for the row consumed NEXT iteration.
  float2 L0, M0, R0, L1, M1, R1;
  loadrow(r0 + 2, L0, M0, R0);

#pragma unroll
  for (int p = 0; p < RP; ++p) {
    if (p + 1 < RP) loadrow(r0 + 3 + p, L1, M1, R1);   // prefetch next row

    hfilt(L0, M0, R0, A[4], B[4], C[4], D[4]);         // consume preloaded row

    f32x4 ev, od;
    ev.x = A[0]*E0 + A[1]*E1 + A[2]*E2 + A[3]*E3 + A[4]*E4;
    ev.y = B[0]*E0 + B[1]*E1 + B[2]*E2 + B[3]*E3 + B[4]*E4;
    ev.z = C[0]*E0 + C[1]*E1 + C[2]*E2 + C[3]*E3 + C[4]*E4;
    ev.w = D[0]*E0 + D[1]*E1 + D[2]*E2 + D[3]*E3 + D[4]*E4;
    od.x = A[1]*O0 + A[2]*O1 + A[3]*O2 + A[4]*O3;
    od.y = B[1]*O0 + B[2]*O1 + B[3]*O2 + B[4]*O3;
    od.z = C[1]*O0 + C[2]*O1 + C[3]*O2 + C[4]*O3;
    od.w = D[1]*O0 + D[2]*O1 + D[3]*O2 + D[4]*O3;

    const int row_e = 2 * (r0 + p);
    f32x4* pe = reinterpret_cast<f32x4*>(&outb[(size_t)row_e       * (2 * W) + 4 * tid]);
    f32x4* po = reinterpret_cast<f32x4*>(&outb[(size_t)(row_e + 1) * (2 * W) + 4 * tid]);
    __builtin_nontemporal_store(ev, pe);
    __builtin_nontemporal_store(od, po);

#pragma unroll
    for (int k = 0; k < 4; ++k) {
      A[k] = A[k + 1]; B[k] = B[k + 1]; C[k] = C[k + 1]; D[k] = D[k + 1];
    }
    L0 = L1; M0 = M1; R0 = R1;
  }
}

extern "C" void kernel_launch(void* const* d_in, const int* in_sizes, int n_in,
                              void* d_out, int out_size, void* d_ws, size_t ws_size,
                              hipStream_t stream) {
  const float* in = (const float*)d_in[0];
  float* out = (float*)d_out;
  const int batch = in_sizes[0] / (H * W);
  dim3 grid(H / RP, batch);   // 64 x 16 = 1024 blocks -> 4 blocks/CU
  bior_up_kernel<<<grid, 256, 0, stream>>>(in, out);
}